// Round 15
// baseline (234.464 us; speedup 1.0000x reference)
//
#include <hip/hip_runtime.h>

typedef unsigned short u16;
typedef unsigned int u32;
typedef __bf16 bf16_t;
typedef bf16_t bf16x8 __attribute__((ext_vector_type(8)));
typedef u16 u16x8 __attribute__((ext_vector_type(8)));
typedef float f32x4 __attribute__((ext_vector_type(4)));

__device__ __forceinline__ float bf2f(u16 u) {
    union { float f; unsigned i; } c; c.i = ((unsigned)u) << 16; return c.f;
}
__device__ __forceinline__ u16 f2bf(float f) {
    return __builtin_bit_cast(u16, (bf16_t)f);   // native v_cvt (RTNE)
}
__device__ __forceinline__ f32x4 mfma16(bf16x8 a, bf16x8 b, f32x4 c) {
    return __builtin_amdgcn_mfma_f32_16x16x32_bf16(a, b, c, 0, 0, 0);
}
__device__ __forceinline__ void gld16(const u16* g, u16* l) {
    __builtin_amdgcn_global_load_lds(
        (const __attribute__((address_space(1))) void*)g,
        (__attribute__((address_space(3))) void*)l, 16, 0, 0);
}
#define SCHED_FENCE() __builtin_amdgcn_sched_barrier(0)

// ---------------------------------------------------------------------------
// f32 -> bf16, 8 elems/thread
// ---------------------------------------------------------------------------
__global__ __launch_bounds__(256)
void cvt_kernel(const float* __restrict__ in, u16* __restrict__ out)
{
    const int i = (blockIdx.x * 256 + threadIdx.x) * 8;
    float4 a = *reinterpret_cast<const float4*>(in + i);
    float4 b = *reinterpret_cast<const float4*>(in + i + 4);
    u16x8 o;
    o[0] = f2bf(a.x); o[1] = f2bf(a.y); o[2] = f2bf(a.z); o[3] = f2bf(a.w);
    o[4] = f2bf(b.x); o[5] = f2bf(b.y); o[6] = f2bf(b.z); o[7] = f2bf(b.w);
    *reinterpret_cast<u16x8*>(out + i) = o;
}

// ---------------------------------------------------------------------------
// f32 [K][N] -> bf16 transposed [N][K]
// ---------------------------------------------------------------------------
__global__ __launch_bounds__(256)
void cvt_t_kernel(const float* __restrict__ in, u16* __restrict__ out,
                  int K, int N)
{
    __shared__ float tile[32][33];
    const int kb = blockIdx.x * 32, nb = blockIdx.y * 32;
    const int r = threadIdx.x >> 3, c4 = threadIdx.x & 7;
    float4 v = *reinterpret_cast<const float4*>(&in[(size_t)(kb + r) * N + nb + c4 * 4]);
    tile[r][c4 * 4 + 0] = v.x; tile[r][c4 * 4 + 1] = v.y;
    tile[r][c4 * 4 + 2] = v.z; tile[r][c4 * 4 + 3] = v.w;
    __syncthreads();
    ushort4 o;
    o.x = f2bf(tile[c4 * 4 + 0][r]);
    o.y = f2bf(tile[c4 * 4 + 1][r]);
    o.z = f2bf(tile[c4 * 4 + 2][r]);
    o.w = f2bf(tile[c4 * 4 + 3][r]);
    *reinterpret_cast<ushort4*>(&out[(size_t)(nb + r) * K + kb + c4 * 4]) = o;
}

// ---------------------------------------------------------------------------
// 128x128 GEMM, 8 waves, per-wave 64x32 (acc 32 AGPR).  R11-proven m97 loop:
// BK=64, single 32 KB LDS buffer.  Used for A and C (+ fallbacks).
// ---------------------------------------------------------------------------
template<int NSPLIT, bool BIAS, bool RELU, bool QSCALE>
__global__ __launch_bounds__(512, 4)
void gemm8w_kernel(const u16* __restrict__ A, const u16* __restrict__ Bt,
                   const float* __restrict__ bias, u16* __restrict__ C,
                   int M, int N, int K)
{
    __shared__ u16 As[128][64];
    __shared__ u16 Bs[128][64];
    const int tid  = threadIdx.x;
    const int lane = tid & 63;
    const int wid  = tid >> 6;
    const int wm = wid >> 2, wn = wid & 3;
    const int bm = blockIdx.x, bn = blockIdx.y;
    const int kg = lane >> 4;
    const int lc = lane & 15;
    const int pk = kg ^ ((lc + (lc >> 2)) & 3);

    f32x4 acc[4][2];
    #pragma unroll
    for (int i = 0; i < 4; ++i)
        #pragma unroll
        for (int j = 0; j < 2; ++j)
            acc[i][j] = f32x4{0.f, 0.f, 0.f, 0.f};

    const int nk = (K >> 6) / NSPLIT;
    const int kbase = (NSPLIT > 1) ? blockIdx.z * nk : 0;

    for (int kt = 0; kt < nk; ++kt) {
        const int ktg = kbase + kt;
        __syncthreads();
        #pragma unroll
        for (int p = 0; p < 2; ++p) {
            int c = p * 512 + tid;
            int row  = c >> 3;
            int half = (c >> 2) & 1;
            int ko   = (((c & 3) ^ ((row + (row >> 2)) & 3)) << 3) + half * 32;
            gld16(A + (size_t)(bm * 128 + row) * K + ktg * 64 + ko,
                  &As[0][0] + c * 8);
            gld16(Bt + (size_t)(bn * 128 + row) * K + ktg * 64 + ko,
                  &Bs[0][0] + c * 8);
        }
        __syncthreads();

        bf16x8 af[4][2], bf[2][2];
        #pragma unroll
        for (int i = 0; i < 4; ++i)
            #pragma unroll
            for (int kk = 0; kk < 2; ++kk)
                af[i][kk] = *reinterpret_cast<const bf16x8*>(
                    &As[wm * 64 + i * 16 + lc][kk * 32 + pk * 8]);
        #pragma unroll
        for (int j = 0; j < 2; ++j)
            #pragma unroll
            for (int kk = 0; kk < 2; ++kk)
                bf[j][kk] = *reinterpret_cast<const bf16x8*>(
                    &Bs[wn * 32 + j * 16 + lc][kk * 32 + pk * 8]);
        #pragma unroll
        for (int j = 0; j < 2; ++j)
            #pragma unroll
            for (int i = 0; i < 4; ++i)
                #pragma unroll
                for (int kk = 0; kk < 2; ++kk)
                    acc[i][j] = mfma16(af[i][kk], bf[j][kk], acc[i][j]);
    }

    u16* Cp = C + (size_t)((NSPLIT > 1) ? blockIdx.z : 0) * M * N;
    const bool addb = BIAS && (NSPLIT == 1 || blockIdx.z == 0);
    #pragma unroll
    for (int i = 0; i < 4; ++i) {
        #pragma unroll
        for (int j = 0; j < 2; ++j) {
            int col = bn * 128 + wn * 32 + j * 16 + lc;
            float bv = addb ? bias[col] : 0.f;
            float qs = 1.0f;
            if (QSCALE) {
                u32 cm = (u32)col % 192u;
                if (cm >= 64u && cm < 128u) qs = 0.1803368875f;  // 0.125*log2e
            }
            #pragma unroll
            for (int r = 0; r < 4; ++r) {
                int row = bm * 128 + wm * 64 + i * 16 + kg * 4 + r;
                float v = acc[i][j][r] + bv;
                if (RELU) v = v > 0.f ? v : 0.f;
                if (QSCALE) v *= qs;
                Cp[(size_t)row * N + col] = f2bf(v);
            }
        }
    }
}

// ---------------------------------------------------------------------------
// 256x256 8-PHASE GEMM (m201 template, adapted).  BK=64, 8 waves (2Mx4N),
// per-wave 128x64 out (acc = 128 AGPR), LDS = 2-K-tile dbuf x (A+B) 256x64
// = 128 KiB, 1 block/CU, launch_bounds(512,2).
// Per K-tile tau: 4 phases, each =
//   { 12 ds_read_b128 (one C-quadrant's frags from buf[tau&1]) ;
//     stage 1 half-tile of tile tau+1 into buf[(tau+1)&1] (2 gld16/thread,
//     order B0,B1,A0,A1) ; barrier ; setprio(1) 16 MFMA setprio(0) ;
//     [phase 4 only: vmcnt(0)] ; barrier }
// Race safety: stages only touch buf[(tau+1)&1], last read in tile tau-1
// whose end-barrier precedes these stages; boundary vmcnt(0)+barrier at
// phase 4 certifies ALL waves' loads for tile tau+1 landed before its reads.
// Swizzle (both-sides): row rl holds source chunk (p ^ g(rl)) at phys p,
// g(rl) = (rl + rl/4) & 7; frag read at row i*16+lc uses
// phys = (kk*4+kg) ^ ((4i + lc + lc/4) & 7)  [same key, verified algebra].
// ---------------------------------------------------------------------------
template<int NSPLIT, bool BIAS, bool RELU>
__global__ __launch_bounds__(512, 2)
void gemm256_kernel(const u16* __restrict__ A, const u16* __restrict__ Bt,
                    const float* __restrict__ bias, u16* __restrict__ C,
                    int M, int N, int K)
{
    __shared__ u16 As[2][256][64];
    __shared__ u16 Bs[2][256][64];
    const int tid  = threadIdx.x;
    const int lane = tid & 63;
    const int wid  = tid >> 6;
    const int wm = wid >> 2, wn = wid & 3;      // 2 x 4 wave grid
    const int bm = blockIdx.x, bn = blockIdx.y;
    const int kg = lane >> 4;
    const int lc = lane & 15;

    f32x4 acc[8][4];
    #pragma unroll
    for (int i = 0; i < 8; ++i)
        #pragma unroll
        for (int j = 0; j < 4; ++j)
            acc[i][j] = f32x4{0.f, 0.f, 0.f, 0.f};

    const int nkt = (K >> 6) / NSPLIT;          // K-tiles of 64
    const int kbase = (NSPLIT > 1) ? blockIdx.z * nkt : 0;

    // stage one half-tile (128 rows x 64 cols) of K-tile tau.
    // part: 0 = B half0, 1 = B half1, 2 = A half0, 3 = A half1.
    auto stage_half = [&](int tau, int part) {
        if (tau >= nkt) return;
        const int buf  = tau & 1;
        const int half = part & 1;
        const int ktg  = kbase + tau;
        const u16* src = (part < 2) ? Bt : A;
        const int  rb  = ((part < 2) ? bn : bm) * 256 + half * 128;
        u16* dst = (part < 2) ? &Bs[buf][half * 128][0] : &As[buf][half * 128][0];
        #pragma unroll
        for (int p = 0; p < 2; ++p) {
            int c  = p * 512 + tid;             // 0..1023
            int rl = c >> 3;                    // 0..127
            int g  = (rl + (rl >> 2)) & 7;
            int sc = ((c & 7) ^ g) * 8;
            gld16(src + (size_t)(rb + rl) * K + ktg * 64 + sc, dst + c * 8);
        }
    };

    // prologue: K-tile 0 fully staged + certified
    #pragma unroll
    for (int part = 0; part < 4; ++part) stage_half(0, part);
    asm volatile("s_waitcnt vmcnt(0)" ::: "memory");
    SCHED_FENCE();
    __builtin_amdgcn_s_barrier();
    SCHED_FENCE();

    for (int tau = 0; tau < nkt; ++tau) {
        const int buf = tau & 1;
        #pragma unroll
        for (int q = 0; q < 4; ++q) {           // quadrant (qi,qj)
            const int qi = q >> 1, qj = q & 1;
            bf16x8 af[4][2], bf[2][2];
            #pragma unroll
            for (int ii = 0; ii < 4; ++ii) {
                const int i = qi * 4 + ii;
                const int g = (4 * i + lc + (lc >> 2)) & 7;
                #pragma unroll
                for (int kk = 0; kk < 2; ++kk) {
                    const int ph = (kk * 4 + kg) ^ g;
                    af[ii][kk] = *reinterpret_cast<const bf16x8*>(
                        &As[buf][wm * 128 + i * 16 + lc][ph * 8]);
                }
            }
            #pragma unroll
            for (int jj = 0; jj < 2; ++jj) {
                const int j = qj * 2 + jj;
                const int g = (4 * j + lc + (lc >> 2)) & 7;
                #pragma unroll
                for (int kk = 0; kk < 2; ++kk) {
                    const int ph = (kk * 4 + kg) ^ g;
                    bf[jj][kk] = *reinterpret_cast<const bf16x8*>(
                        &Bs[buf][wn * 64 + j * 16 + lc][ph * 8]);
                }
            }
            stage_half(tau + 1, q);             // 1 half-tile prefetch/phase
            SCHED_FENCE();
            __builtin_amdgcn_s_barrier();
            SCHED_FENCE();
            __builtin_amdgcn_s_setprio(1);
            #pragma unroll
            for (int jj = 0; jj < 2; ++jj)
                #pragma unroll
                for (int ii = 0; ii < 4; ++ii)
                    #pragma unroll
                    for (int kk = 0; kk < 2; ++kk)
                        acc[qi * 4 + ii][qj * 2 + jj] =
                            mfma16(af[ii][kk], bf[jj][kk],
                                   acc[qi * 4 + ii][qj * 2 + jj]);
            __builtin_amdgcn_s_setprio(0);
            if (q == 3)                          // K-tile boundary only
                asm volatile("s_waitcnt vmcnt(0)" ::: "memory");
            SCHED_FENCE();
            __builtin_amdgcn_s_barrier();
            SCHED_FENCE();
        }
    }

    u16* Cp = C + (size_t)((NSPLIT > 1) ? blockIdx.z : 0) * M * N;
    const bool addb = BIAS && (NSPLIT == 1 || blockIdx.z == 0);
    #pragma unroll
    for (int i = 0; i < 8; ++i) {
        #pragma unroll
        for (int j = 0; j < 4; ++j) {
            int col = bn * 256 + wn * 64 + j * 16 + lc;
            float bv = addb ? bias[col] : 0.f;
            #pragma unroll
            for (int r = 0; r < 4; ++r) {
                int row = bm * 256 + wm * 128 + i * 16 + kg * 4 + r;
                float v = acc[i][j][r] + bv;
                if (RELU) v = v > 0.f ? v : 0.f;
                Cp[(size_t)row * N + col] = f2bf(v);
            }
        }
    }
}

// ---------------------------------------------------------------------------
// qlo[b][s] = last p <= s with tokens[p]==start_id, clamped 0
// ---------------------------------------------------------------------------
__global__ __launch_bounds__(256)
void qlo_kernel(const int* __restrict__ tokens, const int* __restrict__ start_id,
                int* __restrict__ qlo)
{
    constexpr int S = 2048;
    __shared__ int part[256];
    __shared__ int pref[256];
    const int b = blockIdx.x, tid = threadIdx.x;
    const int sid = start_id[0];
    const int base = b * S + tid * 8;
    int f[8]; int loc = -1;
    #pragma unroll
    for (int j = 0; j < 8; ++j) {
        f[j] = (tokens[base + j] == sid) ? 1 : 0;
        if (f[j]) loc = tid * 8 + j;
    }
    part[tid] = loc;
    __syncthreads();
    if (tid == 0) {
        int run = -1;
        for (int i = 0; i < 256; ++i) { pref[i] = run; run = max(run, part[i]); }
    }
    __syncthreads();
    int run = pref[tid];
    #pragma unroll
    for (int j = 0; j < 8; ++j) {
        if (f[j]) run = tid * 8 + j;
        qlo[base + j] = max(run, 0);
    }
}

// ---------------------------------------------------------------------------
// flash attention, causal+segment via qlo window [qlo[q], q].
// ---------------------------------------------------------------------------
#define MASKVAL -60000.0f
#define MINIT   -30000.0f
__global__ __launch_bounds__(256)
void attn_kernel(const u16* __restrict__ qkv, const int* __restrict__ qloA,
                 u16* __restrict__ attn_out)
{
    constexpr int S = 2048, DQ = 3072;
    __shared__ u16 Ks[64][72];
    __shared__ u16 Vt[64][72];
    __shared__ u16 Pt[4][16][72];
    __shared__ int wm4[4];

    const int tid = threadIdx.x;
    const int lane = tid & 63, w = tid >> 6;
    const int kg = lane >> 4, lc = lane & 15;
    const int qt = blockIdx.x, h = blockIdx.y, b = blockIdx.z;
    const size_t rowbase = (size_t)b * S;
    const int colK = h * 192, colQ = colK + 64, colV = colK + 128;
    const int qrow = qt * 64 + w * 16 + lc;

    bf16x8 qf0, qf1;
    {
        const u16* qp = &qkv[(rowbase + qrow) * DQ + colQ];
        qf0 = *reinterpret_cast<const bf16x8*>(qp + kg * 8);
        qf1 = *reinterpret_cast<const bf16x8*>(qp + 32 + kg * 8);
    }
    const int myqlo = qloA[rowbase + qrow];

    int vmin = myqlo;
    #pragma unroll
    for (int m = 1; m < 16; m <<= 1) vmin = min(vmin, __shfl_xor(vmin, m));
    if (lane == 0) wm4[w] = vmin;
    __syncthreads();
    const int kb0 = min(min(wm4[0], wm4[1]), min(wm4[2], wm4[3])) >> 6;

    float m_ = MINIT, l_ = 0.f;
    f32x4 o[4];
    #pragma unroll
    for (int d = 0; d < 4; ++d) o[d] = f32x4{0.f, 0.f, 0.f, 0.f};

    const int kr = tid >> 3, kc = tid & 7;
    const int rpv = tid >> 3, chv = tid & 7;
    uint4 gk0, gk1, gv0, gv1;

    auto issue = [&](int kb) {
        const size_t base = rowbase + (size_t)kb * 64;
        gk0 = *reinterpret_cast<const uint4*>(&qkv[(base + kr) * DQ + colK + kc * 8]);
        gk1 = *reinterpret_cast<const uint4*>(&qkv[(base + 32 + kr) * DQ + colK + kc * 8]);
        const u16* vp = &qkv[(base + rpv * 2) * DQ + colV + chv * 8];
        gv0 = *reinterpret_cast<const uint4*>(vp);
        gv1 = *reinterpret_cast<const uint4*>(vp + DQ);
    };
    auto write_lds = [&]() {
        *reinterpret_cast<uint4*>(&Ks[kr][kc * 8]) = gk0;
        *reinterpret_cast<uint4*>(&Ks[32 + kr][kc * 8]) = gk1;
        u16x8 va = __builtin_bit_cast(u16x8, gv0);
        u16x8 vb = __builtin_bit_cast(u16x8, gv1);
        const int kp = (rpv * 2) ^ (chv << 3);
        #pragma unroll
        for (int j = 0; j < 8; ++j)
            *reinterpret_cast<u32*>(&Vt[chv * 8 + j][kp]) =
                (u32)va[j] | ((u32)vb[j] << 16);
    };

    issue(kb0);
    for (int kb = kb0; kb <= qt; ++kb) {
        write_lds();
        __syncthreads();
        if (kb < qt) issue(kb + 1);

        f32x4 sT[4];
        #pragma unroll
        for (int ks = 0; ks < 4; ++ks) {
            bf16x8 kf0 = *reinterpret_cast<const bf16x8*>(&Ks[ks * 16 + lc][kg * 8]);
            bf16x8 kf1 = *reinterpret_cast<const bf16x8*>(&Ks[ks * 16 + lc][32 + kg * 8]);
            f32x4 s = f32x4{0.f, 0.f, 0.f, 0.f};
            s = mfma16(kf0, qf0, s);
            s = mfma16(kf1, qf1, s);
            sT[ks] = s;
        }
        const int lo = myqlo - kb * 64, hi = qrow - kb * 64;
        #pragma unroll
        for (int ks = 0; ks < 4; ++ks) {
            #pragma unroll
            for (int r = 0; r < 4; ++r) {
                int kk = ks * 16 + kg * 4 + r;
                bool ok = (kk >= lo) && (kk <= hi);
                sT[ks][r] = ok ? sT[ks][r] : MASKVAL;
            }
        }
        float tm = fmaxf(fmaxf(fmaxf(sT[0][0], sT[0][1]), fmaxf(sT[0][2], sT[0][3])),
                         fmaxf(fmaxf(sT[1][0], sT[1][1]), fmaxf(sT[1][2], sT[1][3])));
        tm = fmaxf(tm, fmaxf(fmaxf(fmaxf(sT[2][0], sT[2][1]), fmaxf(sT[2][2], sT[2][3])),
                             fmaxf(fmaxf(sT[3][0], sT[3][1]), fmaxf(sT[3][2], sT[3][3]))));
        tm = fmaxf(tm, __shfl_xor(tm, 16));
        tm = fmaxf(tm, __shfl_xor(tm, 32));
        float mn = fmaxf(m_, tm);
        float al = exp2f(m_ - mn);
        m_ = mn;
        float ps = 0.f;
        #pragma unroll
        for (int ks = 0; ks < 4; ++ks) {
            ushort4 pw;
            float p0 = exp2f(sT[ks][0] - m_); ps += p0; pw.x = f2bf(p0);
            float p1 = exp2f(sT[ks][1] - m_); ps += p1; pw.y = f2bf(p1);
            float p2 = exp2f(sT[ks][2] - m_); ps += p2; pw.z = f2bf(p2);
            float p3 = exp2f(sT[ks][3] - m_); ps += p3; pw.w = f2bf(p3);
            *reinterpret_cast<ushort4*>(&Pt[w][lc][ks * 16 + kg * 4]) = pw;
        }
        ps += __shfl_xor(ps, 16);
        ps += __shfl_xor(ps, 32);
        l_ = l_ * al + ps;
        float alr[4];
        #pragma unroll
        for (int r = 0; r < 4; ++r) alr[r] = __shfl(al, kg * 4 + r);
        #pragma unroll
        for (int d = 0; d < 4; ++d)
            #pragma unroll
            for (int r = 0; r < 4; ++r) o[d][r] *= alr[r];

        #pragma unroll
        for (int kf = 0; kf < 2; ++kf) {
            bf16x8 pf = *reinterpret_cast<const bf16x8*>(&Pt[w][lc][kf * 32 + kg * 8]);
            #pragma unroll
            for (int d = 0; d < 4; ++d) {
                int vrow = d * 16 + lc;
                int b3 = (kf * 4 + kg) ^ ((vrow >> 3) & 7);
                bf16x8 vf = *reinterpret_cast<const bf16x8*>(&Vt[vrow][b3 * 8]);
                o[d] = mfma16(pf, vf, o[d]);
            }
        }
        __syncthreads();
    }

    float lr[4];
    #pragma unroll
    for (int r = 0; r < 4; ++r) lr[r] = __shfl(l_, kg * 4 + r);
    #pragma unroll
    for (int d = 0; d < 4; ++d)
        #pragma unroll
        for (int r = 0; r < 4; ++r) {
            float v = o[d][r] / fmaxf(lr[r], 1e-20f);
            int qo = qt * 64 + w * 16 + kg * 4 + r;
            attn_out[(rowbase + qo) * 1024 + h * 64 + d * 16 + lc] = f2bf(v);
        }
}

// ---------------------------------------------------------------------------
// LayerNorm + residual.  Sums NSPL bf16 partials (stride 4M elems) first.
// ---------------------------------------------------------------------------
template<int NSPL, bool WRITE_BF>
__global__ __launch_bounds__(256)
void ln_kernel(const u16* __restrict__ in, const float* __restrict__ gam,
               const float* __restrict__ bet, const float* res,
               float* out_f, u16* __restrict__ out_bf)
{
    const int row = blockIdx.x;
    const int tid = threadIdx.x;
    const int lane = tid & 63, w = tid >> 6;
    __shared__ float red1[4], red2[4];

    const size_t base = (size_t)row * 1024 + tid * 4;
    float x0 = 0.f, x1 = 0.f, x2 = 0.f, x3 = 0.f;
    #pragma unroll
    for (int sp = 0; sp < NSPL; ++sp) {
        ushort4 xv = *reinterpret_cast<const ushort4*>(in + (size_t)sp * 4194304 + base);
        x0 += bf2f(xv.x); x1 += bf2f(xv.y); x2 += bf2f(xv.z); x3 += bf2f(xv.w);
    }

    float s = x0 + x1 + x2 + x3;
    #pragma unroll
    for (int m = 1; m < 64; m <<= 1) s += __shfl_xor(s, m);
    if (lane == 0) red1[w] = s;
    __syncthreads();
    float mu = (red1[0] + red1[1] + red1[2] + red1[3]) * (1.0f / 1024.0f);

    float d0 = x0 - mu, d1 = x1 - mu, d2 = x2 - mu, d3 = x3 - mu;
    float q = d0 * d0 + d1 * d1 + d2 * d2 + d3 * d3;
    #pragma unroll
    for (int m = 1; m < 64; m <<= 1) q += __shfl_xor(q, m);
    if (lane == 0) red2[w] = q;
    __syncthreads();
    float var = (red2[0] + red2[1] + red2[2] + red2[3]) * (1.0f / 1024.0f);
    float rs = rsqrtf(var + 1e-6f);

    float dd[4] = {d0, d1, d2, d3};
    #pragma unroll
    for (int e = 0; e < 4; ++e) {
        int col = tid * 4 + e;
        size_t idx = (size_t)row * 1024 + col;
        float y = dd[e] * rs * gam[col] + bet[col];
        float ov = y + res[idx];
        out_f[idx] = ov;
        if constexpr (WRITE_BF) out_bf[idx] = f2bf(ov);
    }
}

// ---------------------------------------------------------------------------
// Workspace timeline (MiB offsets):
//   XB [0,8) -> WOBt [0,2) -> x_bf [0,8) -> WDBt [0,8)
//   qkv [8,32) -> cpart [8,24) -> hbuf [8,40)
//   attn_o [32,40)
//   KBt [40,46) + qlo [46M] -> WUBt [40,48)
//   F partials: [40, 40+8*ns)
// d_out (f32 16MB) holds residual x from D to G.
// ---------------------------------------------------------------------------
extern "C" void kernel_launch(void* const* d_in, const int* in_sizes, int n_in,
                              void* d_out, int out_size, void* d_ws, size_t ws_size,
                              hipStream_t stream)
{
    const float* x_emb = (const float*)d_in[0];
    const int* tokens  = (const int*)d_in[1];
    const float* KQV   = (const float*)d_in[2];
    const float* WO    = (const float*)d_in[3];
    const float* W_up  = (const float*)d_in[4];
    const float* b_up  = (const float*)d_in[5];
    const float* W_dn  = (const float*)d_in[6];
    const float* b_dn  = (const float*)d_in[7];
    const float* g1    = (const float*)d_in[8];
    const float* be1   = (const float*)d_in[9];
    const float* g2    = (const float*)d_in[10];
    const float* be2   = (const float*)d_in[11];
    const int* start   = (const int*)d_in[12];

    const size_t MiB = 1048576;
    char* ws = (char*)d_ws;
    u16* XB     = (u16*)(ws + 0);
    u16* qkv    = (u16*)(ws + 8 * MiB);
    u16* attn_o = (u16*)(ws + 32 * MiB);
    u16* KBt    = (u16*)(ws + 40 * MiB);
    int* qloA   = (int*)(ws + 46 * MiB);
    u16* WOBt   = (u16*)(ws + 0);
    u16* cpart  = (u16*)(ws + 8 * MiB);
    u16* x_bf   = (u16*)(ws + 0);
    u16* WUBt   = (u16*)(ws + 40 * MiB);
    u16* hbuf   = (u16*)(ws + 8 * MiB);
    u16* WDBt   = (u16*)(ws + 0);
    u16* fpart  = (u16*)(ws + 40 * MiB);
    float* x_f  = (float*)d_out;
    float* outp = (float*)d_out;

    cvt_kernel<<<2048, 256, 0, stream>>>(x_emb, XB);
    cvt_t_kernel<<<dim3(32, 96), 256, 0, stream>>>(KQV, KBt, 1024, 3072);
    qlo_kernel<<<2, 256, 0, stream>>>(tokens, start, qloA);
    // A. qkv = x_embeds @ KQV (Q pre-scaled) — R11 kernel
    gemm8w_kernel<1, false, false, true><<<dim3(32, 24), 512, 0, stream>>>(XB, KBt, nullptr, qkv, 4096, 3072, 1024);
    cvt_t_kernel<<<dim3(32, 32), 256, 0, stream>>>(WO, WOBt, 1024, 1024);
    // B. attention
    attn_kernel<<<dim3(32, 16, 2), 256, 0, stream>>>(qkv, qloA, attn_o);
    cvt_t_kernel<<<dim3(32, 128), 256, 0, stream>>>(W_up, WUBt, 1024, 4096);
    // C. cpart = attn_o @ WO (split-K=2) — R11 kernel
    gemm8w_kernel<2, false, false, false><<<dim3(32, 8, 2), 512, 0, stream>>>(attn_o, WOBt, nullptr, cpart, 4096, 1024, 1024);
    // D. x = LN1(c0+c1) + x_embeds
    ln_kernel<2, true><<<4096, 256, 0, stream>>>(cpart, g1, be1, x_emb, x_f, x_bf);
    // E. h = relu(x @ W_up + b_up) — 8-phase 256^2, 256 blocks = 1/CU
    gemm256_kernel<1, true, true><<<dim3(16, 16), 512, 0, stream>>>(x_bf, WUBt, b_up, hbuf, 4096, 4096, 1024);
    cvt_t_kernel<<<dim3(128, 32), 256, 0, stream>>>(W_dn, WDBt, 4096, 1024);
    // F. fpart = h @ W_down + b_down (split-K adaptive)
    if (ws_size >= 72 * MiB) {
        gemm256_kernel<4, true, false><<<dim3(16, 4, 4), 512, 0, stream>>>(hbuf, WDBt, b_dn, fpart, 4096, 1024, 4096);
        ln_kernel<4, false><<<4096, 256, 0, stream>>>(fpart, g2, be2, x_f, outp, nullptr);
    } else if (ws_size >= 56 * MiB) {
        gemm8w_kernel<2, true, false, false><<<dim3(32, 8, 2), 512, 0, stream>>>(hbuf, WDBt, b_dn, fpart, 4096, 1024, 4096);
        ln_kernel<2, false><<<4096, 256, 0, stream>>>(fpart, g2, be2, x_f, outp, nullptr);
    } else {
        gemm8w_kernel<1, true, false, false><<<dim3(32, 8), 512, 0, stream>>>(hbuf, WDBt, b_dn, fpart, 4096, 1024, 4096);
        ln_kernel<1, false><<<4096, 256, 0, stream>>>(fpart, g2, be2, x_f, outp, nullptr);
    }
}

// Round 16
// 206.984 us; speedup vs baseline: 1.1328x; 1.1328x over previous
//
#include <hip/hip_runtime.h>

typedef unsigned short u16;
typedef unsigned int u32;
typedef __bf16 bf16_t;
typedef bf16_t bf16x8 __attribute__((ext_vector_type(8)));
typedef u16 u16x8 __attribute__((ext_vector_type(8)));
typedef float f32x4 __attribute__((ext_vector_type(4)));

__device__ __forceinline__ float bf2f(u16 u) {
    union { float f; unsigned i; } c; c.i = ((unsigned)u) << 16; return c.f;
}
__device__ __forceinline__ u16 f2bf(float f) {
    return __builtin_bit_cast(u16, (bf16_t)f);   // native v_cvt (RTNE)
}
__device__ __forceinline__ f32x4 mfma16(bf16x8 a, bf16x8 b, f32x4 c) {
    return __builtin_amdgcn_mfma_f32_16x16x32_bf16(a, b, c, 0, 0, 0);
}
__device__ __forceinline__ void gld16(const u16* g, u16* l) {
    __builtin_amdgcn_global_load_lds(
        (const __attribute__((address_space(1))) void*)g,
        (__attribute__((address_space(3))) void*)l, 16, 0, 0);
}

// ---------------------------------------------------------------------------
// f32 -> bf16, 8 elems/thread
// ---------------------------------------------------------------------------
__global__ __launch_bounds__(256)
void cvt_kernel(const float* __restrict__ in, u16* __restrict__ out)
{
    const int i = (blockIdx.x * 256 + threadIdx.x) * 8;
    float4 a = *reinterpret_cast<const float4*>(in + i);
    float4 b = *reinterpret_cast<const float4*>(in + i + 4);
    u16x8 o;
    o[0] = f2bf(a.x); o[1] = f2bf(a.y); o[2] = f2bf(a.z); o[3] = f2bf(a.w);
    o[4] = f2bf(b.x); o[5] = f2bf(b.y); o[6] = f2bf(b.z); o[7] = f2bf(b.w);
    *reinterpret_cast<u16x8*>(out + i) = o;
}

// ---------------------------------------------------------------------------
// f32 [K][N] -> bf16 transposed [N][K]
// ---------------------------------------------------------------------------
__global__ __launch_bounds__(256)
void cvt_t_kernel(const float* __restrict__ in, u16* __restrict__ out,
                  int K, int N)
{
    __shared__ float tile[32][33];
    const int kb = blockIdx.x * 32, nb = blockIdx.y * 32;
    const int r = threadIdx.x >> 3, c4 = threadIdx.x & 7;
    float4 v = *reinterpret_cast<const float4*>(&in[(size_t)(kb + r) * N + nb + c4 * 4]);
    tile[r][c4 * 4 + 0] = v.x; tile[r][c4 * 4 + 1] = v.y;
    tile[r][c4 * 4 + 2] = v.z; tile[r][c4 * 4 + 3] = v.w;
    __syncthreads();
    ushort4 o;
    o.x = f2bf(tile[c4 * 4 + 0][r]);
    o.y = f2bf(tile[c4 * 4 + 1][r]);
    o.z = f2bf(tile[c4 * 4 + 2][r]);
    o.w = f2bf(tile[c4 * 4 + 3][r]);
    *reinterpret_cast<ushort4*>(&out[(size_t)(nb + r) * K + kb + c4 * 4]) = o;
}

// ---------------------------------------------------------------------------
// 128x128 GEMM, 8 waves, per-wave 64x32 (acc 32 AGPR).  R11-proven m97 loop:
// BK=64, single 32 KB LDS buffer.  Used for A and C (+ fallbacks).
// ---------------------------------------------------------------------------
template<int NSPLIT, bool BIAS, bool RELU, bool QSCALE>
__global__ __launch_bounds__(512, 4)
void gemm8w_kernel(const u16* __restrict__ A, const u16* __restrict__ Bt,
                   const float* __restrict__ bias, u16* __restrict__ C,
                   int M, int N, int K)
{
    __shared__ u16 As[128][64];
    __shared__ u16 Bs[128][64];
    const int tid  = threadIdx.x;
    const int lane = tid & 63;
    const int wid  = tid >> 6;
    const int wm = wid >> 2, wn = wid & 3;
    const int bm = blockIdx.x, bn = blockIdx.y;
    const int kg = lane >> 4;
    const int lc = lane & 15;
    const int pk = kg ^ ((lc + (lc >> 2)) & 3);

    f32x4 acc[4][2];
    #pragma unroll
    for (int i = 0; i < 4; ++i)
        #pragma unroll
        for (int j = 0; j < 2; ++j)
            acc[i][j] = f32x4{0.f, 0.f, 0.f, 0.f};

    const int nk = (K >> 6) / NSPLIT;
    const int kbase = (NSPLIT > 1) ? blockIdx.z * nk : 0;

    for (int kt = 0; kt < nk; ++kt) {
        const int ktg = kbase + kt;
        __syncthreads();
        #pragma unroll
        for (int p = 0; p < 2; ++p) {
            int c = p * 512 + tid;
            int row  = c >> 3;
            int half = (c >> 2) & 1;
            int ko   = (((c & 3) ^ ((row + (row >> 2)) & 3)) << 3) + half * 32;
            gld16(A + (size_t)(bm * 128 + row) * K + ktg * 64 + ko,
                  &As[0][0] + c * 8);
            gld16(Bt + (size_t)(bn * 128 + row) * K + ktg * 64 + ko,
                  &Bs[0][0] + c * 8);
        }
        __syncthreads();

        bf16x8 af[4][2], bf[2][2];
        #pragma unroll
        for (int i = 0; i < 4; ++i)
            #pragma unroll
            for (int kk = 0; kk < 2; ++kk)
                af[i][kk] = *reinterpret_cast<const bf16x8*>(
                    &As[wm * 64 + i * 16 + lc][kk * 32 + pk * 8]);
        #pragma unroll
        for (int j = 0; j < 2; ++j)
            #pragma unroll
            for (int kk = 0; kk < 2; ++kk)
                bf[j][kk] = *reinterpret_cast<const bf16x8*>(
                    &Bs[wn * 32 + j * 16 + lc][kk * 32 + pk * 8]);
        #pragma unroll
        for (int j = 0; j < 2; ++j)
            #pragma unroll
            for (int i = 0; i < 4; ++i)
                #pragma unroll
                for (int kk = 0; kk < 2; ++kk)
                    acc[i][j] = mfma16(af[i][kk], bf[j][kk], acc[i][j]);
    }

    u16* Cp = C + (size_t)((NSPLIT > 1) ? blockIdx.z : 0) * M * N;
    const bool addb = BIAS && (NSPLIT == 1 || blockIdx.z == 0);
    #pragma unroll
    for (int i = 0; i < 4; ++i) {
        #pragma unroll
        for (int j = 0; j < 2; ++j) {
            int col = bn * 128 + wn * 32 + j * 16 + lc;
            float bv = addb ? bias[col] : 0.f;
            float qs = 1.0f;
            if (QSCALE) {
                u32 cm = (u32)col % 192u;
                if (cm >= 64u && cm < 128u) qs = 0.1803368875f;  // 0.125*log2e
            }
            #pragma unroll
            for (int r = 0; r < 4; ++r) {
                int row = bm * 128 + wm * 64 + i * 16 + kg * 4 + r;
                float v = acc[i][j][r] + bv;
                if (RELU) v = v > 0.f ? v : 0.f;
                if (QSCALE) v *= qs;
                Cp[(size_t)row * N + col] = f2bf(v);
            }
        }
    }
}

// ---------------------------------------------------------------------------
// 128x256 GEMM (wide), 8 waves (2x4), per-wave 64x64 out (acc = 64 AGPR).
// R13-proven m97 loop, now BK=64: single 48 KB LDS buffer (same 2 blocks/CU
// residency -- regs cap at 2), 6 gld16/thread per stage, compute split into
// two sequential k-halves (8 frag reads + 16 MFMA each -> live frag regs
// unchanged).  32 MFMA per barrier-pair = half the barrier count of R13.
// Chunk-XOR swizzle per 32-col half pre-applied on global source, same key
// on frag reads (gemm8w's verified scheme).
// ---------------------------------------------------------------------------
template<int NSPLIT, bool BIAS, bool RELU>
__global__ __launch_bounds__(512, 4)
void gemm8ww_kernel(const u16* __restrict__ A, const u16* __restrict__ Bt,
                    const float* __restrict__ bias, u16* __restrict__ C,
                    int M, int N, int K)
{
    __shared__ u16 As[128][64];
    __shared__ u16 Bs[256][64];
    const int tid  = threadIdx.x;
    const int lane = tid & 63;
    const int wid  = tid >> 6;                  // 0..7
    const int wm = wid >> 2, wn = wid & 3;      // 2 x 4 wave grid
    const int bm = blockIdx.x, bn = blockIdx.y;
    const int kg = lane >> 4;
    const int lc = lane & 15;
    const int pk = kg ^ ((lc + (lc >> 2)) & 3);

    f32x4 acc[4][4];
    #pragma unroll
    for (int i = 0; i < 4; ++i)
        #pragma unroll
        for (int j = 0; j < 4; ++j)
            acc[i][j] = f32x4{0.f, 0.f, 0.f, 0.f};

    const int nk = (K >> 6) / NSPLIT;
    const int kbase = (NSPLIT > 1) ? blockIdx.z * nk : 0;

    for (int kt = 0; kt < nk; ++kt) {
        const int ktg = kbase + kt;
        __syncthreads();                        // prev tile fully consumed
        // A tile 128x64: 1024 chunks (2/thread)
        #pragma unroll
        for (int p = 0; p < 2; ++p) {
            int c = p * 512 + tid;
            int row  = c >> 3;
            int half = (c >> 2) & 1;
            int ko   = (((c & 3) ^ ((row + (row >> 2)) & 3)) << 3) + half * 32;
            gld16(A + (size_t)(bm * 128 + row) * K + ktg * 64 + ko,
                  &As[0][0] + c * 8);
        }
        // B tile 256x64: 2048 chunks (4/thread)
        #pragma unroll
        for (int p = 0; p < 4; ++p) {
            int c = p * 512 + tid;
            int row  = c >> 3;
            int half = (c >> 2) & 1;
            int ko   = (((c & 3) ^ ((row + (row >> 2)) & 3)) << 3) + half * 32;
            gld16(Bt + (size_t)(bn * 256 + row) * K + ktg * 64 + ko,
                  &Bs[0][0] + c * 8);
        }
        __syncthreads();                        // staged data visible

        // two sequential k-halves: live frag regs stay at 8 x bf16x8
        #pragma unroll
        for (int kk = 0; kk < 2; ++kk) {
            bf16x8 af[4], bf[4];
            #pragma unroll
            for (int i = 0; i < 4; ++i)
                af[i] = *reinterpret_cast<const bf16x8*>(
                    &As[wm * 64 + i * 16 + lc][kk * 32 + pk * 8]);
            #pragma unroll
            for (int j = 0; j < 4; ++j)
                bf[j] = *reinterpret_cast<const bf16x8*>(
                    &Bs[wn * 64 + j * 16 + lc][kk * 32 + pk * 8]);
            #pragma unroll
            for (int j = 0; j < 4; ++j)
                #pragma unroll
                for (int i = 0; i < 4; ++i)
                    acc[i][j] = mfma16(af[i], bf[j], acc[i][j]);
        }
    }

    u16* Cp = C + (size_t)((NSPLIT > 1) ? blockIdx.z : 0) * M * N;
    const bool addb = BIAS && (NSPLIT == 1 || blockIdx.z == 0);
    #pragma unroll
    for (int i = 0; i < 4; ++i) {
        #pragma unroll
        for (int j = 0; j < 4; ++j) {
            int col = bn * 256 + wn * 64 + j * 16 + lc;
            float bv = addb ? bias[col] : 0.f;
            #pragma unroll
            for (int r = 0; r < 4; ++r) {
                int row = bm * 128 + wm * 64 + i * 16 + kg * 4 + r;
                float v = acc[i][j][r] + bv;
                if (RELU) v = v > 0.f ? v : 0.f;
                Cp[(size_t)row * N + col] = f2bf(v);
            }
        }
    }
}

// ---------------------------------------------------------------------------
// qlo[b][s] = last p <= s with tokens[p]==start_id, clamped 0
// ---------------------------------------------------------------------------
__global__ __launch_bounds__(256)
void qlo_kernel(const int* __restrict__ tokens, const int* __restrict__ start_id,
                int* __restrict__ qlo)
{
    constexpr int S = 2048;
    __shared__ int part[256];
    __shared__ int pref[256];
    const int b = blockIdx.x, tid = threadIdx.x;
    const int sid = start_id[0];
    const int base = b * S + tid * 8;
    int f[8]; int loc = -1;
    #pragma unroll
    for (int j = 0; j < 8; ++j) {
        f[j] = (tokens[base + j] == sid) ? 1 : 0;
        if (f[j]) loc = tid * 8 + j;
    }
    part[tid] = loc;
    __syncthreads();
    if (tid == 0) {
        int run = -1;
        for (int i = 0; i < 256; ++i) { pref[i] = run; run = max(run, part[i]); }
    }
    __syncthreads();
    int run = pref[tid];
    #pragma unroll
    for (int j = 0; j < 8; ++j) {
        if (f[j]) run = tid * 8 + j;
        qlo[base + j] = max(run, 0);
    }
}

// ---------------------------------------------------------------------------
// flash attention, causal+segment via qlo window [qlo[q], q].
// ---------------------------------------------------------------------------
#define MASKVAL -60000.0f
#define MINIT   -30000.0f
__global__ __launch_bounds__(256)
void attn_kernel(const u16* __restrict__ qkv, const int* __restrict__ qloA,
                 u16* __restrict__ attn_out)
{
    constexpr int S = 2048, DQ = 3072;
    __shared__ u16 Ks[64][72];
    __shared__ u16 Vt[64][72];
    __shared__ u16 Pt[4][16][72];
    __shared__ int wm4[4];

    const int tid = threadIdx.x;
    const int lane = tid & 63, w = tid >> 6;
    const int kg = lane >> 4, lc = lane & 15;
    const int qt = blockIdx.x, h = blockIdx.y, b = blockIdx.z;
    const size_t rowbase = (size_t)b * S;
    const int colK = h * 192, colQ = colK + 64, colV = colK + 128;
    const int qrow = qt * 64 + w * 16 + lc;

    bf16x8 qf0, qf1;
    {
        const u16* qp = &qkv[(rowbase + qrow) * DQ + colQ];
        qf0 = *reinterpret_cast<const bf16x8*>(qp + kg * 8);
        qf1 = *reinterpret_cast<const bf16x8*>(qp + 32 + kg * 8);
    }
    const int myqlo = qloA[rowbase + qrow];

    int vmin = myqlo;
    #pragma unroll
    for (int m = 1; m < 16; m <<= 1) vmin = min(vmin, __shfl_xor(vmin, m));
    if (lane == 0) wm4[w] = vmin;
    __syncthreads();
    const int kb0 = min(min(wm4[0], wm4[1]), min(wm4[2], wm4[3])) >> 6;

    float m_ = MINIT, l_ = 0.f;
    f32x4 o[4];
    #pragma unroll
    for (int d = 0; d < 4; ++d) o[d] = f32x4{0.f, 0.f, 0.f, 0.f};

    const int kr = tid >> 3, kc = tid & 7;
    const int rpv = tid >> 3, chv = tid & 7;
    uint4 gk0, gk1, gv0, gv1;

    auto issue = [&](int kb) {
        const size_t base = rowbase + (size_t)kb * 64;
        gk0 = *reinterpret_cast<const uint4*>(&qkv[(base + kr) * DQ + colK + kc * 8]);
        gk1 = *reinterpret_cast<const uint4*>(&qkv[(base + 32 + kr) * DQ + colK + kc * 8]);
        const u16* vp = &qkv[(base + rpv * 2) * DQ + colV + chv * 8];
        gv0 = *reinterpret_cast<const uint4*>(vp);
        gv1 = *reinterpret_cast<const uint4*>(vp + DQ);
    };
    auto write_lds = [&]() {
        *reinterpret_cast<uint4*>(&Ks[kr][kc * 8]) = gk0;
        *reinterpret_cast<uint4*>(&Ks[32 + kr][kc * 8]) = gk1;
        u16x8 va = __builtin_bit_cast(u16x8, gv0);
        u16x8 vb = __builtin_bit_cast(u16x8, gv1);
        const int kp = (rpv * 2) ^ (chv << 3);
        #pragma unroll
        for (int j = 0; j < 8; ++j)
            *reinterpret_cast<u32*>(&Vt[chv * 8 + j][kp]) =
                (u32)va[j] | ((u32)vb[j] << 16);
    };

    issue(kb0);
    for (int kb = kb0; kb <= qt; ++kb) {
        write_lds();
        __syncthreads();
        if (kb < qt) issue(kb + 1);

        f32x4 sT[4];
        #pragma unroll
        for (int ks = 0; ks < 4; ++ks) {
            bf16x8 kf0 = *reinterpret_cast<const bf16x8*>(&Ks[ks * 16 + lc][kg * 8]);
            bf16x8 kf1 = *reinterpret_cast<const bf16x8*>(&Ks[ks * 16 + lc][32 + kg * 8]);
            f32x4 s = f32x4{0.f, 0.f, 0.f, 0.f};
            s = mfma16(kf0, qf0, s);
            s = mfma16(kf1, qf1, s);
            sT[ks] = s;
        }
        const int lo = myqlo - kb * 64, hi = qrow - kb * 64;
        #pragma unroll
        for (int ks = 0; ks < 4; ++ks) {
            #pragma unroll
            for (int r = 0; r < 4; ++r) {
                int kk = ks * 16 + kg * 4 + r;
                bool ok = (kk >= lo) && (kk <= hi);
                sT[ks][r] = ok ? sT[ks][r] : MASKVAL;
            }
        }
        float tm = fmaxf(fmaxf(fmaxf(sT[0][0], sT[0][1]), fmaxf(sT[0][2], sT[0][3])),
                         fmaxf(fmaxf(sT[1][0], sT[1][1]), fmaxf(sT[1][2], sT[1][3])));
        tm = fmaxf(tm, fmaxf(fmaxf(fmaxf(sT[2][0], sT[2][1]), fmaxf(sT[2][2], sT[2][3])),
                             fmaxf(fmaxf(sT[3][0], sT[3][1]), fmaxf(sT[3][2], sT[3][3]))));
        tm = fmaxf(tm, __shfl_xor(tm, 16));
        tm = fmaxf(tm, __shfl_xor(tm, 32));
        float mn = fmaxf(m_, tm);
        float al = exp2f(m_ - mn);
        m_ = mn;
        float ps = 0.f;
        #pragma unroll
        for (int ks = 0; ks < 4; ++ks) {
            ushort4 pw;
            float p0 = exp2f(sT[ks][0] - m_); ps += p0; pw.x = f2bf(p0);
            float p1 = exp2f(sT[ks][1] - m_); ps += p1; pw.y = f2bf(p1);
            float p2 = exp2f(sT[ks][2] - m_); ps += p2; pw.z = f2bf(p2);
            float p3 = exp2f(sT[ks][3] - m_); ps += p3; pw.w = f2bf(p3);
            *reinterpret_cast<ushort4*>(&Pt[w][lc][ks * 16 + kg * 4]) = pw;
        }
        ps += __shfl_xor(ps, 16);
        ps += __shfl_xor(ps, 32);
        l_ = l_ * al + ps;
        float alr[4];
        #pragma unroll
        for (int r = 0; r < 4; ++r) alr[r] = __shfl(al, kg * 4 + r);
        #pragma unroll
        for (int d = 0; d < 4; ++d)
            #pragma unroll
            for (int r = 0; r < 4; ++r) o[d][r] *= alr[r];

        #pragma unroll
        for (int kf = 0; kf < 2; ++kf) {
            bf16x8 pf = *reinterpret_cast<const bf16x8*>(&Pt[w][lc][kf * 32 + kg * 8]);
            #pragma unroll
            for (int d = 0; d < 4; ++d) {
                int vrow = d * 16 + lc;
                int b3 = (kf * 4 + kg) ^ ((vrow >> 3) & 7);
                bf16x8 vf = *reinterpret_cast<const bf16x8*>(&Vt[vrow][b3 * 8]);
                o[d] = mfma16(pf, vf, o[d]);
            }
        }
        __syncthreads();
    }

    float lr[4];
    #pragma unroll
    for (int r = 0; r < 4; ++r) lr[r] = __shfl(l_, kg * 4 + r);
    #pragma unroll
    for (int d = 0; d < 4; ++d)
        #pragma unroll
        for (int r = 0; r < 4; ++r) {
            float v = o[d][r] / fmaxf(lr[r], 1e-20f);
            int qo = qt * 64 + w * 16 + kg * 4 + r;
            attn_out[(rowbase + qo) * 1024 + h * 64 + d * 16 + lc] = f2bf(v);
        }
}

// ---------------------------------------------------------------------------
// LayerNorm + residual.  Sums NSPL bf16 partials (stride 4M elems) first.
// ---------------------------------------------------------------------------
template<int NSPL, bool WRITE_BF>
__global__ __launch_bounds__(256)
void ln_kernel(const u16* __restrict__ in, const float* __restrict__ gam,
               const float* __restrict__ bet, const float* res,
               float* out_f, u16* __restrict__ out_bf)
{
    const int row = blockIdx.x;
    const int tid = threadIdx.x;
    const int lane = tid & 63, w = tid >> 6;
    __shared__ float red1[4], red2[4];

    const size_t base = (size_t)row * 1024 + tid * 4;
    float x0 = 0.f, x1 = 0.f, x2 = 0.f, x3 = 0.f;
    #pragma unroll
    for (int sp = 0; sp < NSPL; ++sp) {
        ushort4 xv = *reinterpret_cast<const ushort4*>(in + (size_t)sp * 4194304 + base);
        x0 += bf2f(xv.x); x1 += bf2f(xv.y); x2 += bf2f(xv.z); x3 += bf2f(xv.w);
    }

    float s = x0 + x1 + x2 + x3;
    #pragma unroll
    for (int m = 1; m < 64; m <<= 1) s += __shfl_xor(s, m);
    if (lane == 0) red1[w] = s;
    __syncthreads();
    float mu = (red1[0] + red1[1] + red1[2] + red1[3]) * (1.0f / 1024.0f);

    float d0 = x0 - mu, d1 = x1 - mu, d2 = x2 - mu, d3 = x3 - mu;
    float q = d0 * d0 + d1 * d1 + d2 * d2 + d3 * d3;
    #pragma unroll
    for (int m = 1; m < 64; m <<= 1) q += __shfl_xor(q, m);
    if (lane == 0) red2[w] = q;
    __syncthreads();
    float var = (red2[0] + red2[1] + red2[2] + red2[3]) * (1.0f / 1024.0f);
    float rs = rsqrtf(var + 1e-6f);

    float dd[4] = {d0, d1, d2, d3};
    #pragma unroll
    for (int e = 0; e < 4; ++e) {
        int col = tid * 4 + e;
        size_t idx = (size_t)row * 1024 + col;
        float y = dd[e] * rs * gam[col] + bet[col];
        float ov = y + res[idx];
        out_f[idx] = ov;
        if constexpr (WRITE_BF) out_bf[idx] = f2bf(ov);
    }
}

// ---------------------------------------------------------------------------
// Workspace timeline (MiB offsets):
//   XB [0,8) -> WOBt [0,2) -> x_bf [0,8) -> WDBt [0,8)
//   qkv [8,32) -> cpart [8,24) -> hbuf [8,40)
//   attn_o [32,40)
//   KBt [40,46) + qlo [46M] -> WUBt [40,48)
//   F partials: [40, 40+8*ns)
// d_out (f32 16MB) holds residual x from D to G.
// ---------------------------------------------------------------------------
extern "C" void kernel_launch(void* const* d_in, const int* in_sizes, int n_in,
                              void* d_out, int out_size, void* d_ws, size_t ws_size,
                              hipStream_t stream)
{
    const float* x_emb = (const float*)d_in[0];
    const int* tokens  = (const int*)d_in[1];
    const float* KQV   = (const float*)d_in[2];
    const float* WO    = (const float*)d_in[3];
    const float* W_up  = (const float*)d_in[4];
    const float* b_up  = (const float*)d_in[5];
    const float* W_dn  = (const float*)d_in[6];
    const float* b_dn  = (const float*)d_in[7];
    const float* g1    = (const float*)d_in[8];
    const float* be1   = (const float*)d_in[9];
    const float* g2    = (const float*)d_in[10];
    const float* be2   = (const float*)d_in[11];
    const int* start   = (const int*)d_in[12];

    const size_t MiB = 1048576;
    char* ws = (char*)d_ws;
    u16* XB     = (u16*)(ws + 0);
    u16* qkv    = (u16*)(ws + 8 * MiB);
    u16* attn_o = (u16*)(ws + 32 * MiB);
    u16* KBt    = (u16*)(ws + 40 * MiB);
    int* qloA   = (int*)(ws + 46 * MiB);
    u16* WOBt   = (u16*)(ws + 0);
    u16* cpart  = (u16*)(ws + 8 * MiB);
    u16* x_bf   = (u16*)(ws + 0);
    u16* WUBt   = (u16*)(ws + 40 * MiB);
    u16* hbuf   = (u16*)(ws + 8 * MiB);
    u16* WDBt   = (u16*)(ws + 0);
    u16* fpart  = (u16*)(ws + 40 * MiB);
    float* x_f  = (float*)d_out;
    float* outp = (float*)d_out;

    cvt_kernel<<<2048, 256, 0, stream>>>(x_emb, XB);
    cvt_t_kernel<<<dim3(32, 96), 256, 0, stream>>>(KQV, KBt, 1024, 3072);
    qlo_kernel<<<2, 256, 0, stream>>>(tokens, start, qloA);
    // A. qkv = x_embeds @ KQV (Q pre-scaled) — R11 kernel
    gemm8w_kernel<1, false, false, true><<<dim3(32, 24), 512, 0, stream>>>(XB, KBt, nullptr, qkv, 4096, 3072, 1024);
    cvt_t_kernel<<<dim3(32, 32), 256, 0, stream>>>(WO, WOBt, 1024, 1024);
    // B. attention
    attn_kernel<<<dim3(32, 16, 2), 256, 0, stream>>>(qkv, qloA, attn_o);
    cvt_t_kernel<<<dim3(32, 128), 256, 0, stream>>>(W_up, WUBt, 1024, 4096);
    // C. cpart = attn_o @ WO (split-K=2) — R11 kernel
    gemm8w_kernel<2, false, false, false><<<dim3(32, 8, 2), 512, 0, stream>>>(attn_o, WOBt, nullptr, cpart, 4096, 1024, 1024);
    // D. x = LN1(c0+c1) + x_embeds
    ln_kernel<2, true><<<4096, 256, 0, stream>>>(cpart, g1, be1, x_emb, x_f, x_bf);
    // E. h = relu(x @ W_up + b_up) — wide kernel BK=64, 512 blocks = 2/CU
    gemm8ww_kernel<1, true, true><<<dim3(32, 16), 512, 0, stream>>>(x_bf, WUBt, b_up, hbuf, 4096, 4096, 1024);
    cvt_t_kernel<<<dim3(128, 32), 256, 0, stream>>>(W_dn, WDBt, 4096, 1024);
    // F. fpart = h @ W_down + b_down (split-K adaptive)
    if (ws_size >= 72 * MiB) {
        gemm8ww_kernel<4, true, false><<<dim3(32, 4, 4), 512, 0, stream>>>(hbuf, WDBt, b_dn, fpart, 4096, 1024, 4096);
        ln_kernel<4, false><<<4096, 256, 0, stream>>>(fpart, g2, be2, x_f, outp, nullptr);
    } else if (ws_size >= 56 * MiB) {
        gemm8w_kernel<2, true, false, false><<<dim3(32, 8, 2), 512, 0, stream>>>(hbuf, WDBt, b_dn, fpart, 4096, 1024, 4096);
        ln_kernel<2, false><<<4096, 256, 0, stream>>>(fpart, g2, be2, x_f, outp, nullptr);
    } else {
        gemm8w_kernel<1, true, false, false><<<dim3(32, 8), 512, 0, stream>>>(hbuf, WDBt, b_dn, fpart, 4096, 1024, 4096);
        ln_kernel<1, false><<<4096, 256, 0, stream>>>(fpart, g2, be2, x_f, outp, nullptr);
    }
}